// Round 1
// baseline (609.935 us; speedup 1.0000x reference)
//
#include <hip/hip_runtime.h>

// ---------------------------------------------------------------------------
// Attention block on MI355X (gfx950), bf16-MFMA pipeline.
//   x:(2,2048,2048) f32;  Wq,Wk,Wv:(2048,2048) f32; Wo:(2048,2048) f32
//   out = ( softmax_causal( (xWq)(xWk)^T / sqrt(128) ) (xWv) ) Wo   : f32
// Stages: cvt x -> bf16 | cvt+transpose weights -> bf16 (Wq pre-scaled by
// 1/sqrt(128)*log2e) | GEMM QK fused | GEMM V (transposed write -> V^T) |
// flash attention | GEMM out (f32 write).
// ---------------------------------------------------------------------------

typedef unsigned short u16;
using bf16x8 = __attribute__((ext_vector_type(8))) short;   // 8 bf16 (4 VGPRs)
using f32x4  = __attribute__((ext_vector_type(4))) float;
using u16x8  = __attribute__((ext_vector_type(8))) unsigned short;
using u16x4  = __attribute__((ext_vector_type(4))) unsigned short;

#define AS1 __attribute__((address_space(1)))
#define AS3 __attribute__((address_space(3)))

__device__ __forceinline__ u16 f2bf(float f) {
    union { float f; unsigned u; } v; v.f = f;
    unsigned r = v.u + 0x7fffu + ((v.u >> 16) & 1u);   // RNE
    return (u16)(r >> 16);
}

__device__ __forceinline__ void gload_lds16(const void* g, void* l) {
    // wave-uniform LDS base; HW adds lane*16
    __builtin_amdgcn_global_load_lds((const AS1 void*)g, (AS3 void*)l, 16, 0, 0);
}

// ---------------- x -> bf16 ----------------
__global__ __launch_bounds__(256) void cvt_x_k(const float* __restrict__ x,
                                               u16* __restrict__ xb) {
    int i = (blockIdx.x * 256 + threadIdx.x) * 4;
    float4 v = *(const float4*)(x + i);
    u16x4 o;
    o[0] = f2bf(v.x); o[1] = f2bf(v.y); o[2] = f2bf(v.z); o[3] = f2bf(v.w);
    *(u16x4*)(xb + i) = o;
}

// ---------------- weights -> bf16, transposed (WT[n][k]) ----------------
// z = 0..3 : Wq (scaled by 1/sqrt(128)*log2(e)), Wk, Wv, Wo
__global__ __launch_bounds__(256) void wcvt_k(const float* __restrict__ Wq,
                                              const float* __restrict__ Wk,
                                              const float* __restrict__ Wv,
                                              const float* __restrict__ Wo,
                                              u16* __restrict__ wt) {
    __shared__ float tile[32][33];
    const int z = blockIdx.z;
    const float* W = (z == 0) ? Wq : (z == 1) ? Wk : (z == 2) ? Wv : Wo;
    const float scale = (z == 0) ? 0.12751744f : 1.0f;  // (1/sqrt(128))*log2(e)
    const int tx = threadIdx.x, ty = threadIdx.y;       // block (32,8)
    const int k0 = blockIdx.x * 32, n0 = blockIdx.y * 32;
#pragma unroll
    for (int j = 0; j < 4; j++)
        tile[ty + j * 8][tx] = W[(size_t)(k0 + ty + j * 8) * 2048 + n0 + tx];
    __syncthreads();
    u16* dst = wt + (size_t)z * 4194304;
#pragma unroll
    for (int j = 0; j < 4; j++)
        dst[(size_t)(n0 + ty + j * 8) * 2048 + k0 + tx] = f2bf(tile[tx][ty + j * 8] * scale);
}

// ---------------- bf16 MFMA GEMM: C(M x N) = A(M x 2048) * BT(N x 2048)^T --
// 128x128 tile, BK=32, 4 waves, global_load_lds staging (m97 structure).
// OMODE: 0 = bf16 C[m*ldc+n], 1 = bf16 transposed C[n*ldc+m], 2 = f32 C[m*ldc+n]
template <int OMODE>
__global__ __launch_bounds__(256) void gemm_k(const u16* __restrict__ A,
                                              const u16* __restrict__ BT,
                                              void* __restrict__ Cp, int ldc) {
    __shared__ u16 As[4096];   // [128][32]
    __shared__ u16 Bs[4096];   // [128][32]  (rows = n, cols = k)
    const int tid = threadIdx.x, ln = tid & 63, w = tid >> 6;
    const int m0 = blockIdx.x * 128, n0 = blockIdx.y * 128;
    f32x4 acc[4][4] = {};

    // staging assignment: instr (r,w) covers 512 elems at (r*4+w)*512, lane adds l*8
    const int e0 = w * 512 + ln * 8;
    const int e1 = (4 + w) * 512 + ln * 8;
    const int ar0 = e0 >> 5, ac0 = e0 & 31;
    const int ar1 = e1 >> 5, ac1 = e1 & 31;
    const u16* Ag0 = A + (size_t)(m0 + ar0) * 2048 + ac0;
    const u16* Ag1 = A + (size_t)(m0 + ar1) * 2048 + ac1;
    const u16* Bg0 = BT + (size_t)(n0 + ar0) * 2048 + ac0;
    const u16* Bg1 = BT + (size_t)(n0 + ar1) * 2048 + ac1;
    u16* As0 = As + w * 512;  u16* As1 = As + (4 + w) * 512;
    u16* Bs0 = Bs + w * 512;  u16* Bs1 = Bs + (4 + w) * 512;

    const int mb = (w >> 1) * 64, nb = (w & 1) * 64;

    for (int k0 = 0; k0 < 2048; k0 += 32) {
        __syncthreads();
        gload_lds16(Ag0 + k0, As0);
        gload_lds16(Ag1 + k0, As1);
        gload_lds16(Bg0 + k0, Bs0);
        gload_lds16(Bg1 + k0, Bs1);
        __syncthreads();
        bf16x8 a[4], b[4];
#pragma unroll
        for (int i = 0; i < 4; i++)
            a[i] = *(const bf16x8*)(As + (mb + i * 16 + (ln & 15)) * 32 + (ln >> 4) * 8);
#pragma unroll
        for (int i = 0; i < 4; i++)
            b[i] = *(const bf16x8*)(Bs + (nb + i * 16 + (ln & 15)) * 32 + (ln >> 4) * 8);
#pragma unroll
        for (int i = 0; i < 4; i++)
#pragma unroll
            for (int j = 0; j < 4; j++)
                acc[i][j] = __builtin_amdgcn_mfma_f32_16x16x32_bf16(a[i], b[j], acc[i][j], 0, 0, 0);
    }

    if (OMODE == 0) {
        u16* C = (u16*)Cp;
#pragma unroll
        for (int i = 0; i < 4; i++)
#pragma unroll
            for (int j = 0; j < 4; j++)
#pragma unroll
                for (int r = 0; r < 4; r++)
                    C[(size_t)(m0 + mb + i * 16 + (ln >> 4) * 4 + r) * ldc +
                      (n0 + nb + j * 16 + (ln & 15))] = f2bf(acc[i][j][r]);
    } else if (OMODE == 1) {
        u16* C = (u16*)Cp;
#pragma unroll
        for (int i = 0; i < 4; i++)
#pragma unroll
            for (int j = 0; j < 4; j++) {
                u16x4 pk;
#pragma unroll
                for (int r = 0; r < 4; r++) pk[r] = f2bf(acc[i][j][r]);
                *(u16x4*)(C + (size_t)(n0 + nb + j * 16 + (ln & 15)) * ldc +
                          (m0 + mb + i * 16 + (ln >> 4) * 4)) = pk;
            }
    } else {
        float* C = (float*)Cp;
#pragma unroll
        for (int i = 0; i < 4; i++)
#pragma unroll
            for (int j = 0; j < 4; j++)
#pragma unroll
                for (int r = 0; r < 4; r++)
                    C[(size_t)(m0 + mb + i * 16 + (ln >> 4) * 4 + r) * ldc +
                      (n0 + nb + j * 16 + (ln & 15))] = acc[i][j][r];
    }
}

// ---------------- flash attention ----------------
// qk: (4096 rows)x4096 bf16, cols [0,2048) = Q*scale, [2048,4096) = K
// vt: (2048 rows = h*128+d) x 4096 bf16  (V^T: vt[d_glob][b*2048+t])
// ctx: (4096)x2048 bf16
// grid (qt=32, bh=32), 256 threads; wave w owns q rows qt*64 + w*16 .. +15.
__global__ __launch_bounds__(256) void attn_k(const u16* __restrict__ qk,
                                              const u16* __restrict__ vt,
                                              u16* __restrict__ ctx) {
    const int qt = blockIdx.x, bh = blockIdx.y;
    const int b = bh >> 4, h = bh & 15;
    const int tid = threadIdx.x, ln = tid & 63, w = tid >> 6;
    __shared__ u16 Ks[64 * 136];      // [kv][d],  pad 8  -> conflict-lite b128 reads
    __shared__ u16 Vs[128 * 72];      // [d][kv],  pad 8
    __shared__ u16 Pl[4][16 * 72];    // per-wave P tile [q][kv], pad 8

    const int q0w = qt * 64 + w * 16;
    bf16x8 qf[4];
    {
        const u16* qb = qk + (size_t)(b * 2048 + q0w + (ln & 15)) * 4096 + h * 128 + (ln >> 4) * 8;
#pragma unroll
        for (int kc = 0; kc < 4; kc++) qf[kc] = *(const bf16x8*)(qb + kc * 32);
    }
    f32x4 o[8] = {};
    float mrow[4], lsum[4];
#pragma unroll
    for (int r = 0; r < 4; r++) { mrow[r] = -3.0e38f; lsum[r] = 0.f; }

    const u16* Kg = qk + (size_t)(b * 2048) * 4096 + 2048 + h * 128;  // + t*4096 + d
    const u16* Vg = vt + (size_t)(h * 128) * 4096 + b * 2048;          // + d*4096 + t

    for (int kb = 0; kb <= qt; ++kb) {
        const int kv0 = kb * 64;
        __syncthreads();
#pragma unroll
        for (int it = 0; it < 4; ++it) {  // K tile 64x128
            int e = (it * 256 + tid) * 8;
            int r = e >> 7, c = e & 127;
            *(u16x8*)(Ks + r * 136 + c) = *(const u16x8*)(Kg + (size_t)(kv0 + r) * 4096 + c);
        }
#pragma unroll
        for (int it = 0; it < 4; ++it) {  // V^T tile 128x64
            int e = (it * 256 + tid) * 8;
            int d = e >> 6, c = e & 63;
            *(u16x8*)(Vs + d * 72 + c) = *(const u16x8*)(Vg + (size_t)d * 4096 + kv0 + c);
        }
        __syncthreads();

        // S = Q K^T  (16 q-rows x 64 kv per wave), log2-domain (scale folded in Wq)
        f32x4 s[4] = {};
#pragma unroll
        for (int kc = 0; kc < 4; ++kc)
#pragma unroll
            for (int nf = 0; nf < 4; ++nf) {
                bf16x8 kf = *(const bf16x8*)(Ks + (nf * 16 + (ln & 15)) * 136 + kc * 32 + (ln >> 4) * 8);
                s[nf] = __builtin_amdgcn_mfma_f32_16x16x32_bf16(qf[kc], kf, s[nf], 0, 0, 0);
            }

        if (kb == qt) {  // causal mask on diagonal block
#pragma unroll
            for (int nf = 0; nf < 4; ++nf) {
                int kva = kv0 + nf * 16 + (ln & 15);
#pragma unroll
                for (int r = 0; r < 4; r++) {
                    int qa = q0w + (ln >> 4) * 4 + r;
                    if (kva > qa) s[nf][r] = -3.0e38f;
                }
            }
        }

        // online softmax per row (rows live on 16-lane groups; reduce over l&15)
#pragma unroll
        for (int r = 0; r < 4; r++) {
            float rm = fmaxf(fmaxf(s[0][r], s[1][r]), fmaxf(s[2][r], s[3][r]));
            rm = fmaxf(rm, __shfl_xor(rm, 1));
            rm = fmaxf(rm, __shfl_xor(rm, 2));
            rm = fmaxf(rm, __shfl_xor(rm, 4));
            rm = fmaxf(rm, __shfl_xor(rm, 8));
            float mn = fmaxf(mrow[r], rm);
            float sc = exp2f(mrow[r] - mn);
            mrow[r] = mn;
            float rs = 0.f;
#pragma unroll
            for (int nf = 0; nf < 4; ++nf) {
                float p = exp2f(s[nf][r] - mn);
                s[nf][r] = p;
                rs += p;
            }
            rs += __shfl_xor(rs, 1); rs += __shfl_xor(rs, 2);
            rs += __shfl_xor(rs, 4); rs += __shfl_xor(rs, 8);
            lsum[r] = lsum[r] * sc + rs;
#pragma unroll
            for (int df = 0; df < 8; ++df) o[df][r] *= sc;
        }

        // P -> per-wave LDS (bf16), then PV (same wave; no barrier needed)
        u16* pw = Pl[w];
#pragma unroll
        for (int nf = 0; nf < 4; ++nf)
#pragma unroll
            for (int r = 0; r < 4; r++)
                pw[((ln >> 4) * 4 + r) * 72 + nf * 16 + (ln & 15)] = f2bf(s[nf][r]);

#pragma unroll
        for (int kc = 0; kc < 2; ++kc) {
            bf16x8 a = *(const bf16x8*)(pw + (ln & 15) * 72 + kc * 32 + (ln >> 4) * 8);
#pragma unroll
            for (int df = 0; df < 8; ++df) {
                bf16x8 vb = *(const bf16x8*)(Vs + (df * 16 + (ln & 15)) * 72 + kc * 32 + (ln >> 4) * 8);
                o[df] = __builtin_amdgcn_mfma_f32_16x16x32_bf16(a, vb, o[df], 0, 0, 0);
            }
        }
    }

    // ctx write
#pragma unroll
    for (int df = 0; df < 8; ++df)
#pragma unroll
        for (int r = 0; r < 4; r++) {
            int qa = q0w + (ln >> 4) * 4 + r;
            ctx[(size_t)(b * 2048 + qa) * 2048 + h * 128 + df * 16 + (ln & 15)] =
                f2bf(o[df][r] / lsum[r]);
        }
}

// ---------------------------------------------------------------------------
extern "C" void kernel_launch(void* const* d_in, const int* in_sizes, int n_in,
                              void* d_out, int out_size, void* d_ws, size_t ws_size,
                              hipStream_t stream) {
    const float* x  = (const float*)d_in[0];
    const float* wq = (const float*)d_in[1];
    const float* wk = (const float*)d_in[2];
    const float* wv = (const float*)d_in[3];
    const float* wo = (const float*)d_in[4];
    float* out = (float*)d_out;

    u16* ws  = (u16*)d_ws;
    u16* xb  = ws;                     //  8,388,608 elems : x bf16 (4096x2048)
    u16* wt  = xb + 8388608;           // 16,777,216 elems : WqT|WkT|WvT|WoT bf16
    u16* qkb = wt + 16777216;          // 16,777,216 elems : [Q*scale | K] (4096x4096)
    u16* vtb = qkb + 16777216;         //  8,388,608 elems : V^T (2048x4096)
    u16* ctx = vtb + 8388608;          //  8,388,608 elems : attention out (4096x2048)
    // total ws use: 117,440,512 bytes

    cvt_x_k<<<8192, 256, 0, stream>>>(x, xb);
    wcvt_k<<<dim3(64, 64, 4), dim3(32, 8), 0, stream>>>(wq, wk, wv, wo, wt);
    gemm_k<0><<<dim3(32, 32), 256, 0, stream>>>(xb, wt, qkb, 4096);                  // Q|K
    gemm_k<1><<<dim3(32, 16), 256, 0, stream>>>(xb, wt + 2 * 4194304, vtb, 4096);    // V^T
    attn_k<<<dim3(32, 32), 256, 0, stream>>>(qkb, vtb, ctx);
    gemm_k<2><<<dim3(32, 16), 256, 0, stream>>>(ctx, wt + 3 * 4194304, out, 2048);   // out
}

// Round 4
// 424.058 us; speedup vs baseline: 1.4383x; 1.4383x over previous
//
#include <hip/hip_runtime.h>

// ---------------------------------------------------------------------------
// Attention block on MI355X (gfx950), bf16-MFMA pipeline.
//   x:(2,2048,2048) f32;  Wq,Wk,Wv:(2048,2048) f32; Wo:(2048,2048) f32
//   out = ( softmax_causal( (xWq)(xWk)^T / sqrt(128) ) (xWv) ) Wo   : f32
// R4 = R2 resubmit (two infra failures, no data): attn_k with paired q-tiles
// (load balance), reg-staged double-buffered K/V prefetch, XOR-swizzled LDS,
// setprio around MFMA.
// ---------------------------------------------------------------------------

typedef unsigned short u16;
using bf16x8 = __attribute__((ext_vector_type(8))) short;   // 8 bf16 (4 VGPRs)
using f32x4  = __attribute__((ext_vector_type(4))) float;
using u16x8  = __attribute__((ext_vector_type(8))) unsigned short;
using u16x4  = __attribute__((ext_vector_type(4))) unsigned short;

#define AS1 __attribute__((address_space(1)))
#define AS3 __attribute__((address_space(3)))

__device__ __forceinline__ u16 f2bf(float f) {
    union { float f; unsigned u; } v; v.f = f;
    unsigned r = v.u + 0x7fffu + ((v.u >> 16) & 1u);   // RNE
    return (u16)(r >> 16);
}

__device__ __forceinline__ void gload_lds16(const void* g, void* l) {
    __builtin_amdgcn_global_load_lds((const AS1 void*)g, (AS3 void*)l, 16, 0, 0);
}

// ---------------- x -> bf16 ----------------
__global__ __launch_bounds__(256) void cvt_x_k(const float* __restrict__ x,
                                               u16* __restrict__ xb) {
    int i = (blockIdx.x * 256 + threadIdx.x) * 4;
    float4 v = *(const float4*)(x + i);
    u16x4 o;
    o[0] = f2bf(v.x); o[1] = f2bf(v.y); o[2] = f2bf(v.z); o[3] = f2bf(v.w);
    *(u16x4*)(xb + i) = o;
}

// ---------------- weights -> bf16, transposed (WT[n][k]) ----------------
__global__ __launch_bounds__(256) void wcvt_k(const float* __restrict__ Wq,
                                              const float* __restrict__ Wk,
                                              const float* __restrict__ Wv,
                                              const float* __restrict__ Wo,
                                              u16* __restrict__ wt) {
    __shared__ float tile[32][33];
    const int z = blockIdx.z;
    const float* W = (z == 0) ? Wq : (z == 1) ? Wk : (z == 2) ? Wv : Wo;
    const float scale = (z == 0) ? 0.12751744f : 1.0f;  // (1/sqrt(128))*log2(e)
    const int tx = threadIdx.x, ty = threadIdx.y;       // block (32,8)
    const int k0 = blockIdx.x * 32, n0 = blockIdx.y * 32;
#pragma unroll
    for (int j = 0; j < 4; j++)
        tile[ty + j * 8][tx] = W[(size_t)(k0 + ty + j * 8) * 2048 + n0 + tx];
    __syncthreads();
    u16* dst = wt + (size_t)z * 4194304;
#pragma unroll
    for (int j = 0; j < 4; j++)
        dst[(size_t)(n0 + ty + j * 8) * 2048 + k0 + tx] = f2bf(tile[tx][ty + j * 8] * scale);
}

// ---------------- bf16 MFMA GEMM (m97 structure, unchanged) ----------------
template <int OMODE>
__global__ __launch_bounds__(256) void gemm_k(const u16* __restrict__ A,
                                              const u16* __restrict__ BT,
                                              void* __restrict__ Cp, int ldc) {
    __shared__ u16 As[4096];   // [128][32]
    __shared__ u16 Bs[4096];   // [128][32]
    const int tid = threadIdx.x, ln = tid & 63, w = tid >> 6;
    const int m0 = blockIdx.x * 128, n0 = blockIdx.y * 128;
    f32x4 acc[4][4] = {};

    const int e0 = w * 512 + ln * 8;
    const int e1 = (4 + w) * 512 + ln * 8;
    const int ar0 = e0 >> 5, ac0 = e0 & 31;
    const int ar1 = e1 >> 5, ac1 = e1 & 31;
    const u16* Ag0 = A + (size_t)(m0 + ar0) * 2048 + ac0;
    const u16* Ag1 = A + (size_t)(m0 + ar1) * 2048 + ac1;
    const u16* Bg0 = BT + (size_t)(n0 + ar0) * 2048 + ac0;
    const u16* Bg1 = BT + (size_t)(n0 + ar1) * 2048 + ac1;
    u16* As0 = As + w * 512;  u16* As1 = As + (4 + w) * 512;
    u16* Bs0 = Bs + w * 512;  u16* Bs1 = Bs + (4 + w) * 512;

    const int mb = (w >> 1) * 64, nb = (w & 1) * 64;

    for (int k0 = 0; k0 < 2048; k0 += 32) {
        __syncthreads();
        gload_lds16(Ag0 + k0, As0);
        gload_lds16(Ag1 + k0, As1);
        gload_lds16(Bg0 + k0, Bs0);
        gload_lds16(Bg1 + k0, Bs1);
        __syncthreads();
        bf16x8 a[4], b[4];
#pragma unroll
        for (int i = 0; i < 4; i++)
            a[i] = *(const bf16x8*)(As + (mb + i * 16 + (ln & 15)) * 32 + (ln >> 4) * 8);
#pragma unroll
        for (int i = 0; i < 4; i++)
            b[i] = *(const bf16x8*)(Bs + (nb + i * 16 + (ln & 15)) * 32 + (ln >> 4) * 8);
#pragma unroll
        for (int i = 0; i < 4; i++)
#pragma unroll
            for (int j = 0; j < 4; j++)
                acc[i][j] = __builtin_amdgcn_mfma_f32_16x16x32_bf16(a[i], b[j], acc[i][j], 0, 0, 0);
    }

    if (OMODE == 0) {
        u16* C = (u16*)Cp;
#pragma unroll
        for (int i = 0; i < 4; i++)
#pragma unroll
            for (int j = 0; j < 4; j++)
#pragma unroll
                for (int r = 0; r < 4; r++)
                    C[(size_t)(m0 + mb + i * 16 + (ln >> 4) * 4 + r) * ldc +
                      (n0 + nb + j * 16 + (ln & 15))] = f2bf(acc[i][j][r]);
    } else if (OMODE == 1) {
        u16* C = (u16*)Cp;
#pragma unroll
        for (int i = 0; i < 4; i++)
#pragma unroll
            for (int j = 0; j < 4; j++) {
                u16x4 pk;
#pragma unroll
                for (int r = 0; r < 4; r++) pk[r] = f2bf(acc[i][j][r]);
                *(u16x4*)(C + (size_t)(n0 + nb + j * 16 + (ln & 15)) * ldc +
                          (m0 + mb + i * 16 + (ln >> 4) * 4)) = pk;
            }
    } else {
        float* C = (float*)Cp;
#pragma unroll
        for (int i = 0; i < 4; i++)
#pragma unroll
            for (int j = 0; j < 4; j++)
#pragma unroll
                for (int r = 0; r < 4; r++)
                    C[(size_t)(m0 + mb + i * 16 + (ln >> 4) * 4 + r) * ldc +
                      (n0 + nb + j * 16 + (ln & 15))] = acc[i][j][r];
    }
}

// ---------------- flash attention v2 ----------------
// qk: (4096)x4096 bf16, cols [0,2048)=Q*scale(log2e), [2048,4096)=K
// vt: (2048 = h*128+d) x 4096 bf16  (V^T)
// ctx: (4096)x2048 bf16
// 512 blocks (1D), 256 threads. Block handles q-tiles {qp, 31-qp} for one
// (b,h): uniform 33 kv-steps. K/V double-buffered + reg-staged prefetch.
__global__ __launch_bounds__(256, 2) void attn_k(const u16* __restrict__ qk,
                                                 const u16* __restrict__ vt,
                                                 u16* __restrict__ ctx) {
    const int bid = blockIdx.x;
    const int xcd = bid & 7, idx = bid >> 3;     // XCD-grouped decode
    const int bh = xcd * 4 + (idx & 3);          // 4 (b,h) groups per XCD
    const int qp = idx >> 2;                     // 0..15
    const int b = bh >> 4, h = bh & 15;
    const int qtA = qp, qtB = 31 - qp;
    const int tid = threadIdx.x, ln = tid & 63, w = tid >> 6;

    __shared__ u16 Ks[2][8192];     // [64][128] bf16, XOR-swizzled
    __shared__ u16 Vs[2][8192];     // [128][64] bf16, XOR-swizzled
    __shared__ u16 Pl[4][16 * 72];  // per-wave P tile [q][kv], pad 8

    const u16* Kg = qk + (size_t)(b * 2048) * 4096 + 2048 + h * 128;  // +t*4096+d
    const u16* Vg = vt + (size_t)(h * 128) * 4096 + b * 2048;         // +d*4096+t

    const int nstA = qtA + 1;
    const int nst = 33;

    // per-thread staging geometry (4 K passes + 4 V passes, 16B each)
    const int skr = tid >> 4, skc = (tid & 15) * 8;   // K: row skr+p*16, col skc
    const int svd = tid >> 3, svc = (tid & 7) * 8;    // V: d svd+p*32, col svc

    u16x8 rg[8];
    auto issue = [&](int s) {
        const int kv0 = (s < nstA ? s : s - nstA) * 64;
#pragma unroll
        for (int p = 0; p < 4; ++p)
            rg[p] = *(const u16x8*)(Kg + (size_t)(kv0 + p * 16 + skr) * 4096 + skc);
#pragma unroll
        for (int p = 0; p < 4; ++p)
            rg[4 + p] = *(const u16x8*)(Vg + (size_t)(p * 32 + svd) * 4096 + kv0 + svc);
    };
    auto writebuf = [&](int bi) {
#pragma unroll
        for (int p = 0; p < 4; ++p) {
            int r = p * 16 + skr;
            int by = (r * 256 + skc * 2) ^ ((r & 7) << 4);
            *(u16x8*)((char*)Ks[bi] + by) = rg[p];
        }
#pragma unroll
        for (int p = 0; p < 4; ++p) {
            int d = p * 32 + svd;
            int by = (d * 128 + svc * 2) ^ ((d & 7) << 4);
            *(u16x8*)((char*)Vs[bi] + by) = rg[4 + p];
        }
    };

    issue(0);
    writebuf(0);     // compiler inserts vmcnt before ds_write
    __syncthreads();
    int cur = 0, s = 0;

    for (int t = 0; t < 2; ++t) {
        const int qt = (t == 0) ? qtA : qtB;
        const int q0w = qt * 64 + w * 16;
        bf16x8 qf[4];
        {
            const u16* qb = qk + (size_t)(b * 2048 + q0w + (ln & 15)) * 4096 +
                            h * 128 + (ln >> 4) * 8;
#pragma unroll
            for (int kc = 0; kc < 4; ++kc) qf[kc] = *(const bf16x8*)(qb + kc * 32);
        }
        f32x4 o[8] = {};
        float mrow[4], lsum[4];
#pragma unroll
        for (int r = 0; r < 4; ++r) { mrow[r] = -3.0e38f; lsum[r] = 0.f; }

        for (int kb = 0; kb <= qt; ++kb, ++s) {
            const bool more = (s + 1 < nst);
            if (more) issue(s + 1);          // prefetch next tile into regs
            const int kv0 = kb * 64;

            // S = Q K^T (16 q-rows x 64 kv per wave), log2 domain
            f32x4 sv[4] = {};
            __builtin_amdgcn_s_setprio(1);
#pragma unroll
            for (int kc = 0; kc < 4; ++kc)
#pragma unroll
                for (int nf = 0; nf < 4; ++nf) {
                    int row = nf * 16 + (ln & 15);
                    int by = (row * 256 + kc * 64 + (ln >> 4) * 16) ^ ((row & 7) << 4);
                    bf16x8 kf = *(const bf16x8*)((const char*)Ks[cur] + by);
                    sv[nf] = __builtin_amdgcn_mfma_f32_16x16x32_bf16(qf[kc], kf, sv[nf], 0, 0, 0);
                }
            __builtin_amdgcn_s_setprio(0);

            if (kb == qt) {  // causal mask on diagonal block
#pragma unroll
                for (int nf = 0; nf < 4; ++nf) {
                    int kva = kv0 + nf * 16 + (ln & 15);
#pragma unroll
                    for (int r = 0; r < 4; r++) {
                        int qa = q0w + (ln >> 4) * 4 + r;
                        if (kva > qa) sv[nf][r] = -3.0e38f;
                    }
                }
            }

            // online softmax (rows on 16-lane groups)
#pragma unroll
            for (int r = 0; r < 4; r++) {
                float rm = fmaxf(fmaxf(sv[0][r], sv[1][r]), fmaxf(sv[2][r], sv[3][r]));
                rm = fmaxf(rm, __shfl_xor(rm, 1));
                rm = fmaxf(rm, __shfl_xor(rm, 2));
                rm = fmaxf(rm, __shfl_xor(rm, 4));
                rm = fmaxf(rm, __shfl_xor(rm, 8));
                float mn = fmaxf(mrow[r], rm);
                float sc = exp2f(mrow[r] - mn);
                mrow[r] = mn;
                float rs = 0.f;
#pragma unroll
                for (int nf = 0; nf < 4; ++nf) {
                    float p = exp2f(sv[nf][r] - mn);
                    sv[nf][r] = p;
                    rs += p;
                }
                rs += __shfl_xor(rs, 1); rs += __shfl_xor(rs, 2);
                rs += __shfl_xor(rs, 4); rs += __shfl_xor(rs, 8);
                lsum[r] = lsum[r] * sc + rs;
#pragma unroll
                for (int df = 0; df < 8; ++df) o[df][r] *= sc;
            }

            // P -> per-wave LDS (bf16), then PV
            u16* pw = Pl[w];
#pragma unroll
            for (int nf = 0; nf < 4; ++nf)
#pragma unroll
                for (int r = 0; r < 4; r++)
                    pw[((ln >> 4) * 4 + r) * 72 + nf * 16 + (ln & 15)] = f2bf(sv[nf][r]);

#pragma unroll
            for (int kc = 0; kc < 2; ++kc) {
                bf16x8 a = *(const bf16x8*)(pw + (ln & 15) * 72 + kc * 32 + (ln >> 4) * 8);
                __builtin_amdgcn_s_setprio(1);
#pragma unroll
                for (int df = 0; df < 8; ++df) {
                    int d = df * 16 + (ln & 15);
                    int by = (d * 128 + kc * 64 + (ln >> 4) * 16) ^ ((d & 7) << 4);
                    bf16x8 vb = *(const bf16x8*)((const char*)Vs[cur] + by);
                    o[df] = __builtin_amdgcn_mfma_f32_16x16x32_bf16(a, vb, o[df], 0, 0, 0);
                }
                __builtin_amdgcn_s_setprio(0);
            }

            if (more) {
                __syncthreads();           // all waves done reading buf[cur]
                writebuf(cur ^ 1);         // vmcnt inserted by compiler
                __syncthreads();           // writes visible before next compute
                cur ^= 1;
            }
        }

        // finalize tile t
#pragma unroll
        for (int df = 0; df < 8; ++df)
#pragma unroll
            for (int r = 0; r < 4; r++) {
                int qa = q0w + (ln >> 4) * 4 + r;
                ctx[(size_t)(b * 2048 + qa) * 2048 + h * 128 + df * 16 + (ln & 15)] =
                    f2bf(o[df][r] / lsum[r]);
            }
    }
}

// ---------------------------------------------------------------------------
extern "C" void kernel_launch(void* const* d_in, const int* in_sizes, int n_in,
                              void* d_out, int out_size, void* d_ws, size_t ws_size,
                              hipStream_t stream) {
    const float* x  = (const float*)d_in[0];
    const float* wq = (const float*)d_in[1];
    const float* wk = (const float*)d_in[2];
    const float* wv = (const float*)d_in[3];
    const float* wo = (const float*)d_in[4];
    float* out = (float*)d_out;

    u16* ws  = (u16*)d_ws;
    u16* xb  = ws;                     //  8,388,608 : x bf16 (4096x2048)
    u16* wt  = xb + 8388608;           // 16,777,216 : WqT|WkT|WvT|WoT bf16
    u16* qkb = wt + 16777216;          // 16,777,216 : [Q*scale | K] (4096x4096)
    u16* vtb = qkb + 16777216;         //  8,388,608 : V^T (2048x4096)
    u16* ctx = vtb + 8388608;          //  8,388,608 : attention out (4096x2048)

    cvt_x_k<<<8192, 256, 0, stream>>>(x, xb);
    wcvt_k<<<dim3(64, 64, 4), dim3(32, 8), 0, stream>>>(wq, wk, wv, wo, wt);
    gemm_k<0><<<dim3(32, 32), 256, 0, stream>>>(xb, wt, qkb, 4096);                  // Q|K
    gemm_k<1><<<dim3(32, 16), 256, 0, stream>>>(xb, wt + 2 * 4194304, vtb, 4096);    // V^T
    attn_k<<<512, 256, 0, stream>>>(qkb, vtb, ctx);
    gemm_k<2><<<dim3(32, 16), 256, 0, stream>>>(ctx, wt + 3 * 4194304, out, 2048);   // out
}